// Round 2
// baseline (3888.637 us; speedup 1.0000x reference)
//
#include <hip/hip_runtime.h>
#include <math.h>

#define HD 1024
#define S1 150
#define BATCH 128
#define MTOK (S1 * BATCH) /* 19200 */
#define WIN 20
#define QKVLD (3 * HD) /* 3072: row stride of qkv slices */

typedef unsigned short bf16_t;

__device__ __forceinline__ float bf2f(unsigned int u16) {
  return __uint_as_float(u16 << 16);
}
__device__ __forceinline__ unsigned short f2bf(float f) {
  unsigned int u = __float_as_uint(f);
  u += 0x7fff + ((u >> 16) & 1);  // round to nearest even
  return (unsigned short)(u >> 16);
}

__device__ __forceinline__ float wave_sum(float v) {
#pragma unroll
  for (int o = 32; o; o >>= 1) v += __shfl_down(v, o, 64);
  return v;
}
__device__ __forceinline__ float wave_max(float v) {
#pragma unroll
  for (int o = 32; o; o >>= 1) v = fmaxf(v, __shfl_down(v, o, 64));
  return v;
}

// ---------------- PE table: pe[s,2i]=sin(2*pi*s*div_i), pe[s,2i+1]=cos ----
__global__ void pe_kernel(float* __restrict__ pe) {
  int s = blockIdx.x;
  double pos = 6.283185307179586476925286766559 * (double)s;
  for (int p = threadIdx.x; p < HD / 2; p += blockDim.x) {
    double dv = exp((double)(2 * p) * (-9.210340371976184 / (double)HD)); // -ln(1e4)/H
    double a = pos * dv;
    pe[s * HD + 2 * p] = (float)sin(a);
    pe[s * HD + 2 * p + 1] = (float)cos(a);
  }
}

// ---------------- x = LN(concat(cls, z^T) + pe), fp32 out (lives in d_out)
__global__ __launch_bounds__(256) void build_x_kernel(
    const float* __restrict__ z, const float* __restrict__ cls,
    const float* __restrict__ pe, const float* __restrict__ g,
    const float* __restrict__ be, float* __restrict__ x) {
  int t = blockIdx.x;
  int b = t / S1, s = t % S1;
  const float* src = (s == 0) ? cls : (z + ((size_t)(s - 1) * BATCH + b) * HD);
  const float* pr = pe + (size_t)s * HD;
  int tid = threadIdx.x;
  float vals[4];
  float sum = 0.f, sq = 0.f;
#pragma unroll
  for (int i = 0; i < 4; i++) {
    int h = tid + i * 256;
    float v = src[h] + pr[h];
    vals[i] = v;
    sum += v;
    sq += v * v;
  }
  __shared__ float shs[4], shq[4];
  __shared__ float sm, sr;
  sum = wave_sum(sum);
  sq = wave_sum(sq);
  int wave = tid >> 6, lane = tid & 63;
  if (!lane) { shs[wave] = sum; shq[wave] = sq; }
  __syncthreads();
  if (!tid) {
    float S = shs[0] + shs[1] + shs[2] + shs[3];
    float Q = shq[0] + shq[1] + shq[2] + shq[3];
    float mean = S * (1.f / HD);
    float var = Q * (1.f / HD) - mean * mean;  // biased, matches jnp.var
    sm = mean;
    sr = rsqrtf(var + 1e-5f);
  }
  __syncthreads();
  float mean = sm, rstd = sr;
  float* xr = x + (size_t)t * HD;
#pragma unroll
  for (int i = 0; i < 4; i++) {
    int h = tid + i * 256;
    xr[h] = (vals[i] - mean) * rstd * g[h] + be[h];
  }
}

// ---------------- zsa = LN(x + sa): x fp32 stride HD, sa/out bf16 stride QKVLD
__global__ __launch_bounds__(256) void ln_residual_kernel(
    const bf16_t* __restrict__ a, const float* __restrict__ r,
    const float* __restrict__ g, const float* __restrict__ be,
    bf16_t* __restrict__ out) {
  int t = blockIdx.x;
  int tid = threadIdx.x;
  const bf16_t* ar = a + (size_t)t * QKVLD;
  const float* rr = r + (size_t)t * HD;
  float vals[4];
  float sum = 0.f, sq = 0.f;
#pragma unroll
  for (int i = 0; i < 4; i++) {
    int h = tid + i * 256;
    float v = bf2f(ar[h]) + rr[h];
    vals[i] = v;
    sum += v;
    sq += v * v;
  }
  __shared__ float shs[4], shq[4];
  __shared__ float sm, sr;
  sum = wave_sum(sum);
  sq = wave_sum(sq);
  int wave = tid >> 6, lane = tid & 63;
  if (!lane) { shs[wave] = sum; shq[wave] = sq; }
  __syncthreads();
  if (!tid) {
    float S = shs[0] + shs[1] + shs[2] + shs[3];
    float Q = shq[0] + shq[1] + shq[2] + shq[3];
    float mean = S * (1.f / HD);
    float var = Q * (1.f / HD) - mean * mean;
    sm = mean;
    sr = rsqrtf(var + 1e-5f);
  }
  __syncthreads();
  float mean = sm, rstd = sr;
  bf16_t* outp = out + (size_t)t * QKVLD;
#pragma unroll
  for (int i = 0; i < 4; i++) {
    int h = tid + i * 256;
    outp[h] = f2bf((vals[i] - mean) * rstd * g[h] + be[h]);
  }
}

// ---------------- tiled GEMM: C(bf16,ldc) = A(AT,lda) @ W(fp32,KxN) + bias
// EPI: 0 = bias only, 1 = bias + exact gelu. fp32 accumulate.
template <typename AT, int EPI>
__global__ __launch_bounds__(256) void gemm_kernel(
    const AT* __restrict__ A, int lda, const float* __restrict__ W,
    const float* __restrict__ bias, bf16_t* __restrict__ C, int ldc,
    int K, int N) {
  __shared__ float As[16][68];  // [k][m], padded
  __shared__ float Ws[16][64];  // [k][n]
  int tid = threadIdx.x;
  int tx = tid & 15, ty = tid >> 4;
  int m0 = blockIdx.y * 64, n0 = blockIdx.x * 64;
  int la_m = tid >> 2, la_k = (tid & 3) << 2;
  int lw_k = tid >> 4, lw_n = (tid & 15) << 2;
  const AT* Ap = A + (size_t)(m0 + la_m) * lda + la_k;
  const float* Wp = W + (size_t)lw_k * N + n0 + lw_n;
  float acc[4][4] = {};
  for (int k0 = 0; k0 < K; k0 += 16) {
    float av[4];
    if constexpr (sizeof(AT) == 4) {
      float4 a4 = *(const float4*)(Ap + k0);
      av[0] = a4.x; av[1] = a4.y; av[2] = a4.z; av[3] = a4.w;
    } else {
      uint2 a2 = *(const uint2*)(Ap + k0);
      av[0] = bf2f(a2.x & 0xffffu); av[1] = bf2f(a2.x >> 16);
      av[2] = bf2f(a2.y & 0xffffu); av[3] = bf2f(a2.y >> 16);
    }
    float4 w4 = *(const float4*)(Wp + (size_t)k0 * N);
    __syncthreads();
    As[la_k + 0][la_m] = av[0];
    As[la_k + 1][la_m] = av[1];
    As[la_k + 2][la_m] = av[2];
    As[la_k + 3][la_m] = av[3];
    *(float4*)&Ws[lw_k][lw_n] = w4;
    __syncthreads();
#pragma unroll
    for (int k = 0; k < 16; k++) {
      float4 a = *(const float4*)&As[k][ty << 2];
      float4 w = *(const float4*)&Ws[k][tx << 2];
      float ar[4] = {a.x, a.y, a.z, a.w};
      float wr[4] = {w.x, w.y, w.z, w.w};
#pragma unroll
      for (int i = 0; i < 4; i++)
#pragma unroll
        for (int j = 0; j < 4; j++) acc[i][j] += ar[i] * wr[j];
    }
  }
  float4 bs = *(const float4*)(bias + n0 + (tx << 2));
  float bb[4] = {bs.x, bs.y, bs.z, bs.w};
#pragma unroll
  for (int i = 0; i < 4; i++) {
    int m = m0 + (ty << 2) + i;
    float v[4];
#pragma unroll
    for (int j = 0; j < 4; j++) {
      float t = acc[i][j] + bb[j];
      if (EPI == 1) t = 0.5f * t * (1.f + erff(t * 0.7071067811865476f));
      v[j] = t;
    }
    uint2 pk;
    pk.x = (unsigned int)f2bf(v[0]) | ((unsigned int)f2bf(v[1]) << 16);
    pk.y = (unsigned int)f2bf(v[2]) | ((unsigned int)f2bf(v[3]) << 16);
    *(uint2*)(C + (size_t)m * ldc + n0 + (tx << 2)) = pk;
  }
}

// ---------------- final GEMM: out[s,b,:] = res + A @ w_m2 + b_m2 (fp32 out)
__global__ __launch_bounds__(256) void gemm_out_kernel(
    const bf16_t* __restrict__ A, int lda, const float* __restrict__ W,
    const float* __restrict__ bias, const bf16_t* __restrict__ res,
    float* __restrict__ out) {
  const int K = HD, N = HD;
  __shared__ float As[16][68];
  __shared__ float Ws[16][64];
  int tid = threadIdx.x;
  int tx = tid & 15, ty = tid >> 4;
  int m0 = blockIdx.y * 64, n0 = blockIdx.x * 64;
  int la_m = tid >> 2, la_k = (tid & 3) << 2;
  int lw_k = tid >> 4, lw_n = (tid & 15) << 2;
  const bf16_t* Ap = A + (size_t)(m0 + la_m) * lda + la_k;
  const float* Wp = W + (size_t)lw_k * N + n0 + lw_n;
  float acc[4][4] = {};
  for (int k0 = 0; k0 < K; k0 += 16) {
    uint2 a2 = *(const uint2*)(Ap + k0);
    float4 w4 = *(const float4*)(Wp + (size_t)k0 * N);
    __syncthreads();
    As[la_k + 0][la_m] = bf2f(a2.x & 0xffffu);
    As[la_k + 1][la_m] = bf2f(a2.x >> 16);
    As[la_k + 2][la_m] = bf2f(a2.y & 0xffffu);
    As[la_k + 3][la_m] = bf2f(a2.y >> 16);
    *(float4*)&Ws[lw_k][lw_n] = w4;
    __syncthreads();
#pragma unroll
    for (int k = 0; k < 16; k++) {
      float4 a = *(const float4*)&As[k][ty << 2];
      float4 w = *(const float4*)&Ws[k][tx << 2];
      float ar[4] = {a.x, a.y, a.z, a.w};
      float wr[4] = {w.x, w.y, w.z, w.w};
#pragma unroll
      for (int i = 0; i < 4; i++)
#pragma unroll
        for (int j = 0; j < 4; j++) acc[i][j] += ar[i] * wr[j];
    }
  }
  float4 bs = *(const float4*)(bias + n0 + (tx << 2));
  float bb[4] = {bs.x, bs.y, bs.z, bs.w};
#pragma unroll
  for (int i = 0; i < 4; i++) {
    int m = m0 + (ty << 2) + i;
    int b = m / S1, s = m % S1;
    uint2 r2 = *(const uint2*)(res + (size_t)m * QKVLD + n0 + (tx << 2));
    float rr[4] = {bf2f(r2.x & 0xffffu), bf2f(r2.x >> 16),
                   bf2f(r2.y & 0xffffu), bf2f(r2.y >> 16)};
    float4 o;
    float* po = (float*)&o;
#pragma unroll
    for (int j = 0; j < 4; j++) po[j] = acc[i][j] + bb[j] + rr[j];
    *(float4*)(out + ((size_t)s * BATCH + b) * HD + n0 + (tx << 2)) = o;
  }
}

// ---------------- fused band attention; av overwrites own Q row in-place --
__global__ __launch_bounds__(256) void attn_kernel(bf16_t* __restrict__ qkv) {
  int qi = blockIdx.x, b = blockIdx.y;
  bf16_t* qp = qkv + ((size_t)b * S1 + qi) * QKVLD;       // own q row (read then overwritten)
  const bf16_t* kbase = qkv + (size_t)b * S1 * QKVLD + HD;
  const bf16_t* vbase = qkv + (size_t)b * S1 * QKVLD + 2 * HD;
  __shared__ float qs[HD];
  __shared__ float probs[S1];
  __shared__ float rb1[4], rb2[4];
  int tid = threadIdx.x;
  int wave = tid >> 6, lane = tid & 63;
  for (int h = tid; h < HD; h += 256) qs[h] = bf2f(qp[h]);
  for (int c = tid; c < S1; c += 256) probs[c] = 0.f;
  __syncthreads();
  int lo = (qi == 0) ? 0 : (qi - WIN > 0 ? qi - WIN : 0);
  int hi = (qi == 0) ? S1 : (qi + WIN < S1 ? qi + WIN : S1);
  for (int c = lo + wave; c < hi; c += 4) {
    const bf16_t* kr = kbase + (size_t)c * QKVLD;
    float s = 0.f;
#pragma unroll
    for (int i = 0; i < HD / 64; i++) s += qs[lane + i * 64] * bf2f(kr[lane + i * 64]);
    s = wave_sum(s);
    if (!lane) probs[c] = s * 0.03125f;  // 1/sqrt(1024)
  }
  __syncthreads();
  float lm = -1e30f;
  for (int c = lo + tid; c < hi; c += 256) lm = fmaxf(lm, probs[c]);
  lm = wave_max(lm);
  if (!lane) rb1[wave] = lm;
  __syncthreads();
  float bmax = fmaxf(fmaxf(rb1[0], rb1[1]), fmaxf(rb1[2], rb1[3]));
  float ls = 0.f;
  for (int c = lo + tid; c < hi; c += 256) {
    float e = expf(probs[c] - bmax);
    probs[c] = e;
    ls += e;
  }
  ls = wave_sum(ls);
  if (!lane) rb2[wave] = ls;
  __syncthreads();
  float inv = 1.f / (rb2[0] + rb2[1] + rb2[2] + rb2[3]);
  for (int c = lo + tid; c < hi; c += 256) probs[c] *= inv;
  __syncthreads();
#pragma unroll
  for (int i = 0; i < 4; i++) {
    int h = tid + i * 256;
    float acc = 0.f;
    for (int c = lo; c < hi; ++c) acc += probs[c] * bf2f(vbase[(size_t)c * QKVLD + h]);
    qp[h] = f2bf(acc);  // av in place of own q row
  }
}

extern "C" void kernel_launch(void* const* d_in, const int* in_sizes, int n_in,
                              void* d_out, int out_size, void* d_ws, size_t ws_size,
                              hipStream_t stream) {
  (void)in_sizes; (void)n_in; (void)out_size; (void)ws_size;
  const float* z = (const float*)d_in[0];
  const float* cls = (const float*)d_in[1];
  const float* ln_g = (const float*)d_in[2];
  const float* ln_b = (const float*)d_in[3];
  const float* w_qkv = (const float*)d_in[4];
  const float* b_qkv = (const float*)d_in[5];
  const float* w_o = (const float*)d_in[6];
  const float* b_o = (const float*)d_in[7];
  const float* w_m1 = (const float*)d_in[8];
  const float* b_m1 = (const float*)d_in[9];
  const float* w_m2 = (const float*)d_in[10];
  const float* b_m2 = (const float*)d_in[11];

  // Workspace: pe (fp32, 0.6 MB) + qkv (bf16, 118 MB). Total ~118.6 MB.
  float* pe = (float*)d_ws;
  bf16_t* qkv = (bf16_t*)((char*)d_ws + (size_t)S1 * HD * sizeof(float));
  // x lives in d_out (fp32, exactly out_size elems); dead before final store.
  float* x = (float*)d_out;
  // Slice overlays inside qkv (all row-stride QKVLD):
  bf16_t* av = qkv;            // attention writes over Q-slice
  bf16_t* sa = qkv + HD;       // W_o output over K-slice
  bf16_t* zsa = qkv + 2 * HD;  // LN output over V-slice
  bf16_t* h1 = qkv;            // MLP hidden over Q-slice (av dead by then)
  float* out = (float*)d_out;

  pe_kernel<<<S1, 256, 0, stream>>>(pe);
  build_x_kernel<<<MTOK, 256, 0, stream>>>(z, cls, pe, ln_g, ln_b, x);
  gemm_kernel<float, 0><<<dim3(3 * HD / 64, MTOK / 64), 256, 0, stream>>>(
      x, HD, w_qkv, b_qkv, qkv, QKVLD, HD, 3 * HD);
  attn_kernel<<<dim3(S1, BATCH), 256, 0, stream>>>(qkv);
  gemm_kernel<bf16_t, 0><<<dim3(HD / 64, MTOK / 64), 256, 0, stream>>>(
      av, QKVLD, w_o, b_o, sa, QKVLD, HD, HD);
  ln_residual_kernel<<<MTOK, 256, 0, stream>>>(sa, x, ln_g, ln_b, zsa);
  gemm_kernel<bf16_t, 1><<<dim3(HD / 64, MTOK / 64), 256, 0, stream>>>(
      zsa, QKVLD, w_m1, b_m1, h1, QKVLD, HD, HD);
  gemm_out_kernel<<<dim3(HD / 64, MTOK / 64), 256, 0, stream>>>(
      h1, QKVLD, w_m2, b_m2, zsa, out);
}

// Round 3
// 1120.754 us; speedup vs baseline: 3.4697x; 3.4697x over previous
//
#include <hip/hip_runtime.h>
#include <math.h>

#define HD 1024
#define S1 150
#define BATCH 128
#define MTOK (S1 * BATCH) /* 19200 */
#define WIN 20
#define QKVLD (3 * HD) /* 3072 */

typedef unsigned short bf16_t;
typedef short s16x8 __attribute__((ext_vector_type(8)));
typedef float f32x4 __attribute__((ext_vector_type(4)));

__device__ __forceinline__ float bf2f(unsigned int u16) {
  return __uint_as_float(u16 << 16);
}
__device__ __forceinline__ unsigned short f2bf(float f) {
  unsigned int u = __float_as_uint(f);
  u += 0x7fff + ((u >> 16) & 1);  // RNE
  return (unsigned short)(u >> 16);
}

__device__ __forceinline__ float wave_sum(float v) {
#pragma unroll
  for (int o = 32; o; o >>= 1) v += __shfl_down(v, o, 64);
  return v;
}
__device__ __forceinline__ float wave_max(float v) {
#pragma unroll
  for (int o = 32; o; o >>= 1) v = fmaxf(v, __shfl_down(v, o, 64));
  return v;
}

// async 16B/lane global->LDS. LDS dest = wave-uniform base + lane*16.
__device__ __forceinline__ void gload_lds16(const bf16_t* g, bf16_t* l) {
  __builtin_amdgcn_global_load_lds(
      (const __attribute__((address_space(1))) unsigned int*)(unsigned long long)(const void*)g,
      (__attribute__((address_space(3))) unsigned int*)(unsigned int)(unsigned long long)(void*)l,
      16, 0, 0);
}

// ---------------- weight transpose+convert: WT[n][k] = bf16(W[k][n]) ------
__global__ __launch_bounds__(256) void transpose_kernel(
    const float* __restrict__ W, bf16_t* __restrict__ WT, int K, int N) {
  __shared__ float t[32][33];
  int n0 = blockIdx.x * 32, k0 = blockIdx.y * 32;
  int tx = threadIdx.x, ty = threadIdx.y;
#pragma unroll
  for (int i = 0; i < 4; i++)
    t[ty + i * 8][tx] = W[(size_t)(k0 + ty + i * 8) * N + n0 + tx];
  __syncthreads();
#pragma unroll
  for (int i = 0; i < 4; i++)
    WT[(size_t)(n0 + ty + i * 8) * K + k0 + tx] = f2bf(t[tx][ty + i * 8]);
}

// ---------------- PE table ------------------------------------------------
__global__ void pe_kernel(float* __restrict__ pe) {
  int s = blockIdx.x;
  double pos = 6.283185307179586476925286766559 * (double)s;
  for (int p = threadIdx.x; p < HD / 2; p += blockDim.x) {
    double dv = exp((double)(2 * p) * (-9.210340371976184 / (double)HD));
    double a = pos * dv;
    pe[s * HD + 2 * p] = (float)sin(a);
    pe[s * HD + 2 * p + 1] = (float)cos(a);
  }
}

// ---------------- x = bf16(LN(concat(cls, z^T) + pe)) ---------------------
__global__ __launch_bounds__(256) void build_x_kernel(
    const float* __restrict__ z, const float* __restrict__ cls,
    const float* __restrict__ pe, const float* __restrict__ g,
    const float* __restrict__ be, bf16_t* __restrict__ x) {
  int t = blockIdx.x;
  int b = t / S1, s = t % S1;
  const float* src = (s == 0) ? cls : (z + ((size_t)(s - 1) * BATCH + b) * HD);
  const float* pr = pe + (size_t)s * HD;
  int tid = threadIdx.x;
  float vals[4];
  float sum = 0.f, sq = 0.f;
#pragma unroll
  for (int i = 0; i < 4; i++) {
    int h = tid + i * 256;
    float v = src[h] + pr[h];
    vals[i] = v;
    sum += v;
    sq += v * v;
  }
  __shared__ float shs[4], shq[4];
  __shared__ float sm, sr;
  sum = wave_sum(sum);
  sq = wave_sum(sq);
  int wave = tid >> 6, lane = tid & 63;
  if (!lane) { shs[wave] = sum; shq[wave] = sq; }
  __syncthreads();
  if (!tid) {
    float S = shs[0] + shs[1] + shs[2] + shs[3];
    float Q = shq[0] + shq[1] + shq[2] + shq[3];
    float mean = S * (1.f / HD);
    float var = Q * (1.f / HD) - mean * mean;
    sm = mean;
    sr = rsqrtf(var + 1e-5f);
  }
  __syncthreads();
  float mean = sm, rstd = sr;
  bf16_t* xr = x + (size_t)t * HD;
#pragma unroll
  for (int i = 0; i < 4; i++) {
    int h = tid + i * 256;
    xr[h] = f2bf((vals[i] - mean) * rstd * g[h] + be[h]);
  }
}

// ---------------- zsa = bf16(LN(sa + x)) ----------------------------------
__global__ __launch_bounds__(256) void ln_residual_kernel(
    const bf16_t* __restrict__ a, const bf16_t* __restrict__ r,
    const float* __restrict__ g, const float* __restrict__ be,
    bf16_t* __restrict__ out) {
  int t = blockIdx.x;
  int tid = threadIdx.x;
  const bf16_t* ar = a + (size_t)t * QKVLD;
  const bf16_t* rr = r + (size_t)t * HD;
  float vals[4];
  float sum = 0.f, sq = 0.f;
#pragma unroll
  for (int i = 0; i < 4; i++) {
    int h = tid + i * 256;
    float v = bf2f(ar[h]) + bf2f(rr[h]);
    vals[i] = v;
    sum += v;
    sq += v * v;
  }
  __shared__ float shs[4], shq[4];
  __shared__ float sm, sr;
  sum = wave_sum(sum);
  sq = wave_sum(sq);
  int wave = tid >> 6, lane = tid & 63;
  if (!lane) { shs[wave] = sum; shq[wave] = sq; }
  __syncthreads();
  if (!tid) {
    float S = shs[0] + shs[1] + shs[2] + shs[3];
    float Q = shq[0] + shq[1] + shq[2] + shq[3];
    float mean = S * (1.f / HD);
    float var = Q * (1.f / HD) - mean * mean;
    sm = mean;
    sr = rsqrtf(var + 1e-5f);
  }
  __syncthreads();
  float mean = sm, rstd = sr;
  bf16_t* outp = out + (size_t)t * QKVLD;
#pragma unroll
  for (int i = 0; i < 4; i++) {
    int h = tid + i * 256;
    outp[h] = f2bf((vals[i] - mean) * rstd * g[h] + be[h]);
  }
}

// ---------------- MFMA GEMM: C(bf16) = A(M x 1024, bf16) @ WT^T + bias ----
// WT is [N][K=1024] bf16 (pre-transposed). 128x128 tile, BK=32, 4 waves,
// 4x4 grid of 16x16x32 MFMA per wave. global_load_lds staging with chunk-XOR
// swizzle (global-side permutation; LDS stays lane-contiguous).
// EPI: 0 = bias, 1 = bias+gelu
template <int EPI>
__global__ __launch_bounds__(256) void mfma_gemm_kernel(
    const bf16_t* __restrict__ A, int lda, const bf16_t* __restrict__ WT,
    const float* __restrict__ bias, bf16_t* __restrict__ C, int ldc, int N) {
  constexpr int K = 1024;
  __shared__ bf16_t As[128 * 32];
  __shared__ bf16_t Bs[128 * 32];
  int tid = threadIdx.x;
  int w = tid >> 6, lane = tid & 63;
  int wm = w >> 1, wn = w & 1;
  int m0 = blockIdx.y * 128, n0 = blockIdx.x * 128;

  // staging: lane covers row R+(l>>2), LDS slot l&3; fetches global chunk
  // c = (l&3) ^ ((l>>3)&3)  [slot = c ^ ((row>>1)&3)]
  int srow = lane >> 2;
  int scol = ((lane & 3) ^ ((lane >> 3) & 3)) * 8;
  const bf16_t* gA0 = A + (size_t)(m0 + w * 32 + srow) * lda + scol;
  const bf16_t* gA1 = gA0 + (size_t)16 * lda;
  const bf16_t* gB0 = WT + (size_t)(n0 + w * 32 + srow) * K + scol;
  const bf16_t* gB1 = gB0 + (size_t)16 * K;
  bf16_t* lA0 = As + (w * 32) * 32;
  bf16_t* lA1 = As + (w * 32 + 16) * 32;
  bf16_t* lB0 = Bs + (w * 32) * 32;
  bf16_t* lB1 = Bs + (w * 32 + 16) * 32;

  // fragment offsets: row = tile*16 + (lane&15), chunk = lane>>4,
  // slot = chunk ^ ((row>>1)&3)
  int frow = lane & 15;
  int slot = (lane >> 4) ^ ((frow >> 1) & 3);
  int aoff[4], boff[4];
#pragma unroll
  for (int t = 0; t < 4; t++) {
    aoff[t] = (wm * 64 + t * 16 + frow) * 32 + slot * 8;
    boff[t] = (wn * 64 + t * 16 + frow) * 32 + slot * 8;
  }

  f32x4 acc[4][4] = {};

  for (int k0 = 0; k0 < K; k0 += 32) {
    gload_lds16(gA0, lA0);
    gload_lds16(gA1, lA1);
    gload_lds16(gB0, lB0);
    gload_lds16(gB1, lB1);
    gA0 += 32; gA1 += 32; gB0 += 32; gB1 += 32;
    __syncthreads();  // drains vmcnt(0): LDS tiles complete
    s16x8 af[4], bf[4];
#pragma unroll
    for (int t = 0; t < 4; t++) {
      af[t] = *(const s16x8*)(As + aoff[t]);
      bf[t] = *(const s16x8*)(Bs + boff[t]);
    }
#pragma unroll
    for (int i = 0; i < 4; i++)
#pragma unroll
      for (int j = 0; j < 4; j++)
        acc[i][j] = __builtin_amdgcn_mfma_f32_16x16x32_bf16(af[i], bf[j], acc[i][j], 0, 0, 0);
    __syncthreads();  // all reads done before next stage overwrites
  }

  // C/D layout: col = lane&15, row = (lane>>4)*4 + reg
  int erow = (lane >> 4) * 4, ecol = lane & 15;
#pragma unroll
  for (int j = 0; j < 4; j++) {
    int n = n0 + wn * 64 + j * 16 + ecol;
    float bb = bias[n];
#pragma unroll
    for (int i = 0; i < 4; i++) {
      int mb = m0 + wm * 64 + i * 16 + erow;
#pragma unroll
      for (int r = 0; r < 4; r++) {
        float v = acc[i][j][r] + bb;
        if (EPI == 1) v = 0.5f * v * (1.f + erff(v * 0.7071067811865476f));
        C[(size_t)(mb + r) * ldc + n] = f2bf(v);
      }
    }
  }
}

// ---------------- final MFMA GEMM: out[s,b,:] = res + A @ WT^T + bias -----
__global__ __launch_bounds__(256) void mfma_gemm_out_kernel(
    const bf16_t* __restrict__ A, int lda, const bf16_t* __restrict__ WT,
    const float* __restrict__ bias, const bf16_t* __restrict__ res,
    float* __restrict__ out) {
  constexpr int K = 1024;
  __shared__ bf16_t As[128 * 32];
  __shared__ bf16_t Bs[128 * 32];
  int tid = threadIdx.x;
  int w = tid >> 6, lane = tid & 63;
  int wm = w >> 1, wn = w & 1;
  int m0 = blockIdx.y * 128, n0 = blockIdx.x * 128;

  int srow = lane >> 2;
  int scol = ((lane & 3) ^ ((lane >> 3) & 3)) * 8;
  const bf16_t* gA0 = A + (size_t)(m0 + w * 32 + srow) * lda + scol;
  const bf16_t* gA1 = gA0 + (size_t)16 * lda;
  const bf16_t* gB0 = WT + (size_t)(n0 + w * 32 + srow) * K + scol;
  const bf16_t* gB1 = gB0 + (size_t)16 * K;
  bf16_t* lA0 = As + (w * 32) * 32;
  bf16_t* lA1 = As + (w * 32 + 16) * 32;
  bf16_t* lB0 = Bs + (w * 32) * 32;
  bf16_t* lB1 = Bs + (w * 32 + 16) * 32;

  int frow = lane & 15;
  int slot = (lane >> 4) ^ ((frow >> 1) & 3);
  int aoff[4], boff[4];
#pragma unroll
  for (int t = 0; t < 4; t++) {
    aoff[t] = (wm * 64 + t * 16 + frow) * 32 + slot * 8;
    boff[t] = (wn * 64 + t * 16 + frow) * 32 + slot * 8;
  }

  f32x4 acc[4][4] = {};

  for (int k0 = 0; k0 < K; k0 += 32) {
    gload_lds16(gA0, lA0);
    gload_lds16(gA1, lA1);
    gload_lds16(gB0, lB0);
    gload_lds16(gB1, lB1);
    gA0 += 32; gA1 += 32; gB0 += 32; gB1 += 32;
    __syncthreads();
    s16x8 af[4], bf[4];
#pragma unroll
    for (int t = 0; t < 4; t++) {
      af[t] = *(const s16x8*)(As + aoff[t]);
      bf[t] = *(const s16x8*)(Bs + boff[t]);
    }
#pragma unroll
    for (int i = 0; i < 4; i++)
#pragma unroll
      for (int j = 0; j < 4; j++)
        acc[i][j] = __builtin_amdgcn_mfma_f32_16x16x32_bf16(af[i], bf[j], acc[i][j], 0, 0, 0);
    __syncthreads();
  }

  int erow = (lane >> 4) * 4, ecol = lane & 15;
#pragma unroll
  for (int j = 0; j < 4; j++) {
    int n = n0 + wn * 64 + j * 16 + ecol;
    float bb = bias[n];
#pragma unroll
    for (int i = 0; i < 4; i++) {
      int mb = m0 + wm * 64 + i * 16 + erow;
#pragma unroll
      for (int r = 0; r < 4; r++) {
        int m = mb + r;
        int b = m / S1, s = m % S1;
        float v = acc[i][j][r] + bb + bf2f(res[(size_t)m * QKVLD + n]);
        out[((size_t)s * BATCH + b) * HD + n] = v;
      }
    }
  }
}

// ---------------- fused band attention (in-place over Q slice) ------------
__global__ __launch_bounds__(256) void attn_kernel(bf16_t* __restrict__ qkv) {
  int qi = blockIdx.x, b = blockIdx.y;
  bf16_t* qp = qkv + ((size_t)b * S1 + qi) * QKVLD;
  const bf16_t* kbase = qkv + (size_t)b * S1 * QKVLD + HD;
  const bf16_t* vbase = qkv + (size_t)b * S1 * QKVLD + 2 * HD;
  __shared__ float qs[HD];
  __shared__ float probs[S1];
  __shared__ float rb1[4], rb2[4];
  int tid = threadIdx.x;
  int wave = tid >> 6, lane = tid & 63;
  for (int h = tid; h < HD; h += 256) qs[h] = bf2f(qp[h]);
  for (int c = tid; c < S1; c += 256) probs[c] = 0.f;
  __syncthreads();
  int lo = (qi == 0) ? 0 : (qi - WIN > 0 ? qi - WIN : 0);
  int hi = (qi == 0) ? S1 : (qi + WIN < S1 ? qi + WIN : S1);
  for (int c = lo + wave; c < hi; c += 4) {
    const bf16_t* kr = kbase + (size_t)c * QKVLD;
    float s = 0.f;
#pragma unroll
    for (int i = 0; i < HD / 64; i++) s += qs[lane + i * 64] * bf2f(kr[lane + i * 64]);
    s = wave_sum(s);
    if (!lane) probs[c] = s * 0.03125f;
  }
  __syncthreads();
  float lm = -1e30f;
  for (int c = lo + tid; c < hi; c += 256) lm = fmaxf(lm, probs[c]);
  lm = wave_max(lm);
  if (!lane) rb1[wave] = lm;
  __syncthreads();
  float bmax = fmaxf(fmaxf(rb1[0], rb1[1]), fmaxf(rb1[2], rb1[3]));
  float ls = 0.f;
  for (int c = lo + tid; c < hi; c += 256) {
    float e = expf(probs[c] - bmax);
    probs[c] = e;
    ls += e;
  }
  ls = wave_sum(ls);
  if (!lane) rb2[wave] = ls;
  __syncthreads();
  float inv = 1.f / (rb2[0] + rb2[1] + rb2[2] + rb2[3]);
  for (int c = lo + tid; c < hi; c += 256) probs[c] *= inv;
  __syncthreads();
#pragma unroll
  for (int i = 0; i < 4; i++) {
    int h = tid + i * 256;
    float acc = 0.f;
    for (int c = lo; c < hi; ++c) acc += probs[c] * bf2f(vbase[(size_t)c * QKVLD + h]);
    qp[h] = f2bf(acc);
  }
}

extern "C" void kernel_launch(void* const* d_in, const int* in_sizes, int n_in,
                              void* d_out, int out_size, void* d_ws, size_t ws_size,
                              hipStream_t stream) {
  (void)in_sizes; (void)n_in; (void)out_size; (void)ws_size;
  const float* z = (const float*)d_in[0];
  const float* cls = (const float*)d_in[1];
  const float* ln_g = (const float*)d_in[2];
  const float* ln_b = (const float*)d_in[3];
  const float* w_qkv = (const float*)d_in[4];
  const float* b_qkv = (const float*)d_in[5];
  const float* w_o = (const float*)d_in[6];
  const float* b_o = (const float*)d_in[7];
  const float* w_m1 = (const float*)d_in[8];
  const float* b_m1 = (const float*)d_in[9];
  const float* w_m2 = (const float*)d_in[10];
  const float* b_m2 = (const float*)d_in[11];

  // ws: [wt_m2 2MB][pe 0.6MB][qkv 118MB] = ~120.7 MB
  char* wsb = (char*)d_ws;
  bf16_t* wt_m2 = (bf16_t*)wsb;
  float* pe = (float*)(wsb + 2097152);
  bf16_t* qkv = (bf16_t*)(wsb + 2097152 + 614400);

  // d_out scratch: [x bf16 39.3MB][wt_qkv 6.3MB][wt_o 2MB][wt_m1 2MB]
  // All dead before mfma_gemm_out_kernel writes d_out.
  char* outb = (char*)d_out;
  bf16_t* x = (bf16_t*)outb;
  bf16_t* wt_qkv = (bf16_t*)(outb + 39321600);
  bf16_t* wt_o = (bf16_t*)(outb + 45613056);
  bf16_t* wt_m1 = (bf16_t*)(outb + 47710208);

  bf16_t* av = qkv;            // attention writes over Q slice
  bf16_t* sa = qkv + HD;       // over K slice (dead after attention)
  bf16_t* zsa = qkv + 2 * HD;  // over V slice (dead after attention)
  bf16_t* h1 = qkv;            // over Q slice (av dead)
  float* out = (float*)d_out;

  transpose_kernel<<<dim3(96, 32), dim3(32, 8), 0, stream>>>(w_qkv, wt_qkv, HD, 3 * HD);
  transpose_kernel<<<dim3(32, 32), dim3(32, 8), 0, stream>>>(w_o, wt_o, HD, HD);
  transpose_kernel<<<dim3(32, 32), dim3(32, 8), 0, stream>>>(w_m1, wt_m1, HD, HD);
  transpose_kernel<<<dim3(32, 32), dim3(32, 8), 0, stream>>>(w_m2, wt_m2, HD, HD);
  pe_kernel<<<S1, 256, 0, stream>>>(pe);
  build_x_kernel<<<MTOK, 256, 0, stream>>>(z, cls, pe, ln_g, ln_b, x);
  mfma_gemm_kernel<0><<<dim3(24, 150), 256, 0, stream>>>(
      x, HD, wt_qkv, b_qkv, qkv, QKVLD, 3 * HD);
  attn_kernel<<<dim3(S1, BATCH), 256, 0, stream>>>(qkv);
  mfma_gemm_kernel<0><<<dim3(8, 150), 256, 0, stream>>>(
      av, QKVLD, wt_o, b_o, sa, QKVLD, HD);
  ln_residual_kernel<<<MTOK, 256, 0, stream>>>(sa, x, ln_g, ln_b, zsa);
  mfma_gemm_kernel<1><<<dim3(8, 150), 256, 0, stream>>>(
      zsa, QKVLD, wt_m1, b_m1, h1, QKVLD, HD);
  mfma_gemm_out_kernel<<<dim3(8, 150), 256, 0, stream>>>(
      h1, QKVLD, wt_m2, b_m2, zsa, out);
}

// Round 4
// 802.295 us; speedup vs baseline: 4.8469x; 1.3969x over previous
//
#include <hip/hip_runtime.h>
#include <math.h>

#define HD 1024
#define S1 150
#define BATCH 128
#define MTOK (S1 * BATCH) /* 19200 */
#define WIN 20
#define QKVLD (3 * HD) /* 3072 */

typedef unsigned short bf16_t;
typedef short s16x8 __attribute__((ext_vector_type(8)));
typedef float f32x4 __attribute__((ext_vector_type(4)));

__device__ __forceinline__ float bf2f(unsigned int u16) {
  return __uint_as_float(u16 << 16);
}
__device__ __forceinline__ unsigned short f2bf(float f) {
  unsigned int u = __float_as_uint(f);
  u += 0x7fff + ((u >> 16) & 1);  // RNE
  return (unsigned short)(u >> 16);
}

__device__ __forceinline__ float wave_sum(float v) {
#pragma unroll
  for (int o = 32; o; o >>= 1) v += __shfl_down(v, o, 64);
  return v;
}
__device__ __forceinline__ float wave_max(float v) {
#pragma unroll
  for (int o = 32; o; o >>= 1) v = fmaxf(v, __shfl_down(v, o, 64));
  return v;
}

// async 16B/lane global->LDS. LDS dest = wave-uniform base + lane*16.
__device__ __forceinline__ void gload_lds16(const bf16_t* g, bf16_t* l) {
  __builtin_amdgcn_global_load_lds(
      (const __attribute__((address_space(1))) unsigned int*)(unsigned long long)(const void*)g,
      (__attribute__((address_space(3))) unsigned int*)(unsigned int)(unsigned long long)(void*)l,
      16, 0, 0);
}

// ---------------- weight transpose+convert: WT[n][k] = bf16(W[k][n]) ------
__global__ __launch_bounds__(256) void transpose_kernel(
    const float* __restrict__ W, bf16_t* __restrict__ WT, int K, int N) {
  __shared__ float t[32][33];
  int n0 = blockIdx.x * 32, k0 = blockIdx.y * 32;
  int tx = threadIdx.x, ty = threadIdx.y;
#pragma unroll
  for (int i = 0; i < 4; i++)
    t[ty + i * 8][tx] = W[(size_t)(k0 + ty + i * 8) * N + n0 + tx];
  __syncthreads();
#pragma unroll
  for (int i = 0; i < 4; i++)
    WT[(size_t)(n0 + ty + i * 8) * K + k0 + tx] = f2bf(t[tx][ty + i * 8]);
}

// ---------------- PE table ------------------------------------------------
__global__ void pe_kernel(float* __restrict__ pe) {
  int s = blockIdx.x;
  double pos = 6.283185307179586476925286766559 * (double)s;
  for (int p = threadIdx.x; p < HD / 2; p += blockDim.x) {
    double dv = exp((double)(2 * p) * (-9.210340371976184 / (double)HD));
    double a = pos * dv;
    pe[s * HD + 2 * p] = (float)sin(a);
    pe[s * HD + 2 * p + 1] = (float)cos(a);
  }
}

// ---------------- x = bf16(LN(concat(cls, z^T) + pe)) ---------------------
__global__ __launch_bounds__(256) void build_x_kernel(
    const float* __restrict__ z, const float* __restrict__ cls,
    const float* __restrict__ pe, const float* __restrict__ g,
    const float* __restrict__ be, bf16_t* __restrict__ x) {
  int t = blockIdx.x;
  int b = t / S1, s = t % S1;
  const float* src = (s == 0) ? cls : (z + ((size_t)(s - 1) * BATCH + b) * HD);
  const float* pr = pe + (size_t)s * HD;
  int tid = threadIdx.x;
  float vals[4];
  float sum = 0.f, sq = 0.f;
#pragma unroll
  for (int i = 0; i < 4; i++) {
    int h = tid + i * 256;
    float v = src[h] + pr[h];
    vals[i] = v;
    sum += v;
    sq += v * v;
  }
  __shared__ float shs[4], shq[4];
  __shared__ float sm, sr;
  sum = wave_sum(sum);
  sq = wave_sum(sq);
  int wave = tid >> 6, lane = tid & 63;
  if (!lane) { shs[wave] = sum; shq[wave] = sq; }
  __syncthreads();
  if (!tid) {
    float S = shs[0] + shs[1] + shs[2] + shs[3];
    float Q = shq[0] + shq[1] + shq[2] + shq[3];
    float mean = S * (1.f / HD);
    float var = Q * (1.f / HD) - mean * mean;
    sm = mean;
    sr = rsqrtf(var + 1e-5f);
  }
  __syncthreads();
  float mean = sm, rstd = sr;
  bf16_t* xr = x + (size_t)t * HD;
#pragma unroll
  for (int i = 0; i < 4; i++) {
    int h = tid + i * 256;
    xr[h] = f2bf((vals[i] - mean) * rstd * g[h] + be[h]);
  }
}

// ---------------- zsa = bf16(LN(sa + x)) ----------------------------------
__global__ __launch_bounds__(256) void ln_residual_kernel(
    const bf16_t* __restrict__ a, const bf16_t* __restrict__ r,
    const float* __restrict__ g, const float* __restrict__ be,
    bf16_t* __restrict__ out) {
  int t = blockIdx.x;
  int tid = threadIdx.x;
  const bf16_t* ar = a + (size_t)t * QKVLD;
  const bf16_t* rr = r + (size_t)t * HD;
  float vals[4];
  float sum = 0.f, sq = 0.f;
#pragma unroll
  for (int i = 0; i < 4; i++) {
    int h = tid + i * 256;
    float v = bf2f(ar[h]) + bf2f(rr[h]);
    vals[i] = v;
    sum += v;
    sq += v * v;
  }
  __shared__ float shs[4], shq[4];
  __shared__ float sm, sr;
  sum = wave_sum(sum);
  sq = wave_sum(sq);
  int wave = tid >> 6, lane = tid & 63;
  if (!lane) { shs[wave] = sum; shq[wave] = sq; }
  __syncthreads();
  if (!tid) {
    float S = shs[0] + shs[1] + shs[2] + shs[3];
    float Q = shq[0] + shq[1] + shq[2] + shq[3];
    float mean = S * (1.f / HD);
    float var = Q * (1.f / HD) - mean * mean;
    sm = mean;
    sr = rsqrtf(var + 1e-5f);
  }
  __syncthreads();
  float mean = sm, rstd = sr;
  bf16_t* outp = out + (size_t)t * QKVLD;
#pragma unroll
  for (int i = 0; i < 4; i++) {
    int h = tid + i * 256;
    outp[h] = f2bf((vals[i] - mean) * rstd * g[h] + be[h]);
  }
}

// ---------------- MFMA GEMM: C(bf16) = A(M x 1024, bf16) @ WT^T + bias ----
template <int EPI>
__global__ __launch_bounds__(256) void mfma_gemm_kernel(
    const bf16_t* __restrict__ A, int lda, const bf16_t* __restrict__ WT,
    const float* __restrict__ bias, bf16_t* __restrict__ C, int ldc, int N) {
  constexpr int K = 1024;
  __shared__ bf16_t As[128 * 32];
  __shared__ bf16_t Bs[128 * 32];
  int tid = threadIdx.x;
  int w = tid >> 6, lane = tid & 63;
  int wm = w >> 1, wn = w & 1;
  int m0 = blockIdx.y * 128, n0 = blockIdx.x * 128;

  int srow = lane >> 2;
  int scol = ((lane & 3) ^ ((lane >> 3) & 3)) * 8;
  const bf16_t* gA0 = A + (size_t)(m0 + w * 32 + srow) * lda + scol;
  const bf16_t* gA1 = gA0 + (size_t)16 * lda;
  const bf16_t* gB0 = WT + (size_t)(n0 + w * 32 + srow) * K + scol;
  const bf16_t* gB1 = gB0 + (size_t)16 * K;
  bf16_t* lA0 = As + (w * 32) * 32;
  bf16_t* lA1 = As + (w * 32 + 16) * 32;
  bf16_t* lB0 = Bs + (w * 32) * 32;
  bf16_t* lB1 = Bs + (w * 32 + 16) * 32;

  int frow = lane & 15;
  int slot = (lane >> 4) ^ ((frow >> 1) & 3);
  int aoff[4], boff[4];
#pragma unroll
  for (int t = 0; t < 4; t++) {
    aoff[t] = (wm * 64 + t * 16 + frow) * 32 + slot * 8;
    boff[t] = (wn * 64 + t * 16 + frow) * 32 + slot * 8;
  }

  f32x4 acc[4][4] = {};

  for (int k0 = 0; k0 < K; k0 += 32) {
    gload_lds16(gA0, lA0);
    gload_lds16(gA1, lA1);
    gload_lds16(gB0, lB0);
    gload_lds16(gB1, lB1);
    gA0 += 32; gA1 += 32; gB0 += 32; gB1 += 32;
    __syncthreads();
    s16x8 af[4], bf[4];
#pragma unroll
    for (int t = 0; t < 4; t++) {
      af[t] = *(const s16x8*)(As + aoff[t]);
      bf[t] = *(const s16x8*)(Bs + boff[t]);
    }
#pragma unroll
    for (int i = 0; i < 4; i++)
#pragma unroll
      for (int j = 0; j < 4; j++)
        acc[i][j] = __builtin_amdgcn_mfma_f32_16x16x32_bf16(af[i], bf[j], acc[i][j], 0, 0, 0);
    __syncthreads();
  }

  int erow = (lane >> 4) * 4, ecol = lane & 15;
#pragma unroll
  for (int j = 0; j < 4; j++) {
    int n = n0 + wn * 64 + j * 16 + ecol;
    float bb = bias[n];
#pragma unroll
    for (int i = 0; i < 4; i++) {
      int mb = m0 + wm * 64 + i * 16 + erow;
#pragma unroll
      for (int r = 0; r < 4; r++) {
        float v = acc[i][j][r] + bb;
        if (EPI == 1) v = 0.5f * v * (1.f + erff(v * 0.7071067811865476f));
        C[(size_t)(mb + r) * ldc + n] = f2bf(v);
      }
    }
  }
}

// ---------------- final MFMA GEMM: out[s,b,:] = res + A @ WT^T + bias -----
__global__ __launch_bounds__(256) void mfma_gemm_out_kernel(
    const bf16_t* __restrict__ A, int lda, const bf16_t* __restrict__ WT,
    const float* __restrict__ bias, const bf16_t* __restrict__ res,
    float* __restrict__ out) {
  constexpr int K = 1024;
  __shared__ bf16_t As[128 * 32];
  __shared__ bf16_t Bs[128 * 32];
  int tid = threadIdx.x;
  int w = tid >> 6, lane = tid & 63;
  int wm = w >> 1, wn = w & 1;
  int m0 = blockIdx.y * 128, n0 = blockIdx.x * 128;

  int srow = lane >> 2;
  int scol = ((lane & 3) ^ ((lane >> 3) & 3)) * 8;
  const bf16_t* gA0 = A + (size_t)(m0 + w * 32 + srow) * lda + scol;
  const bf16_t* gA1 = gA0 + (size_t)16 * lda;
  const bf16_t* gB0 = WT + (size_t)(n0 + w * 32 + srow) * K + scol;
  const bf16_t* gB1 = gB0 + (size_t)16 * K;
  bf16_t* lA0 = As + (w * 32) * 32;
  bf16_t* lA1 = As + (w * 32 + 16) * 32;
  bf16_t* lB0 = Bs + (w * 32) * 32;
  bf16_t* lB1 = Bs + (w * 32 + 16) * 32;

  int frow = lane & 15;
  int slot = (lane >> 4) ^ ((frow >> 1) & 3);
  int aoff[4], boff[4];
#pragma unroll
  for (int t = 0; t < 4; t++) {
    aoff[t] = (wm * 64 + t * 16 + frow) * 32 + slot * 8;
    boff[t] = (wn * 64 + t * 16 + frow) * 32 + slot * 8;
  }

  f32x4 acc[4][4] = {};

  for (int k0 = 0; k0 < K; k0 += 32) {
    gload_lds16(gA0, lA0);
    gload_lds16(gA1, lA1);
    gload_lds16(gB0, lB0);
    gload_lds16(gB1, lB1);
    gA0 += 32; gA1 += 32; gB0 += 32; gB1 += 32;
    __syncthreads();
    s16x8 af[4], bf[4];
#pragma unroll
    for (int t = 0; t < 4; t++) {
      af[t] = *(const s16x8*)(As + aoff[t]);
      bf[t] = *(const s16x8*)(Bs + boff[t]);
    }
#pragma unroll
    for (int i = 0; i < 4; i++)
#pragma unroll
      for (int j = 0; j < 4; j++)
        acc[i][j] = __builtin_amdgcn_mfma_f32_16x16x32_bf16(af[i], bf[j], acc[i][j], 0, 0, 0);
    __syncthreads();
  }

  int erow = (lane >> 4) * 4, ecol = lane & 15;
#pragma unroll
  for (int j = 0; j < 4; j++) {
    int n = n0 + wn * 64 + j * 16 + ecol;
    float bb = bias[n];
#pragma unroll
    for (int i = 0; i < 4; i++) {
      int mb = m0 + wm * 64 + i * 16 + erow;
#pragma unroll
      for (int r = 0; r < 4; r++) {
        int m = mb + r;
        int b = m / S1, s = m % S1;
        float v = acc[i][j][r] + bb + bf2f(res[(size_t)m * QKVLD + n]);
        out[((size_t)s * BATCH + b) * HD + n] = v;
      }
    }
  }
}

// ---------------- fused band attention, vectorized (in-place over Q) ------
// Q in registers (16 elems/lane), K cols via 2x dwordx4/lane, PV via uint2.
__global__ __launch_bounds__(256) void attn_kernel(bf16_t* __restrict__ qkv) {
  int qi = blockIdx.x, b = blockIdx.y;
  bf16_t* qp = qkv + ((size_t)b * S1 + qi) * QKVLD;
  const bf16_t* kbase = qkv + (size_t)b * S1 * QKVLD + HD;
  const bf16_t* vbase = qkv + (size_t)b * S1 * QKVLD + 2 * HD;
  __shared__ float probs[S1];
  __shared__ float rb1[4], rb2[4];
  int tid = threadIdx.x;
  int wave = tid >> 6, lane = tid & 63;
  int lo = (qi == 0) ? 0 : (qi - WIN > 0 ? qi - WIN : 0);
  int hi = (qi == 0) ? S1 : (qi + WIN < S1 ? qi + WIN : S1);

  // Q row -> registers: lane holds elems [lane*16, lane*16+16)
  float qf[16];
  {
    uint4 a = *(const uint4*)(qp + lane * 16);
    uint4 c4 = *(const uint4*)(qp + lane * 16 + 8);
    unsigned int u[8] = {a.x, a.y, a.z, a.w, c4.x, c4.y, c4.z, c4.w};
#pragma unroll
    for (int i = 0; i < 8; i++) {
      qf[2 * i] = bf2f(u[i] & 0xffffu);
      qf[2 * i + 1] = bf2f(u[i] >> 16);
    }
  }

  // scores: waves take cols round-robin; 2 vector loads per col
  for (int c = lo + wave; c < hi; c += 4) {
    const bf16_t* kr = kbase + (size_t)c * QKVLD + lane * 16;
    uint4 a = *(const uint4*)kr;
    uint4 c4 = *(const uint4*)(kr + 8);
    unsigned int u[8] = {a.x, a.y, a.z, a.w, c4.x, c4.y, c4.z, c4.w};
    float s = 0.f;
#pragma unroll
    for (int i = 0; i < 8; i++) {
      s += qf[2 * i] * bf2f(u[i] & 0xffffu);
      s += qf[2 * i + 1] * bf2f(u[i] >> 16);
    }
    s = wave_sum(s);
    if (!lane) probs[c] = s * 0.03125f;  // 1/sqrt(1024)
  }
  __syncthreads();

  // softmax over [lo,hi)
  float lm = -1e30f;
  for (int c = lo + tid; c < hi; c += 256) lm = fmaxf(lm, probs[c]);
  lm = wave_max(lm);
  if (!lane) rb1[wave] = lm;
  __syncthreads();
  float bmax = fmaxf(fmaxf(rb1[0], rb1[1]), fmaxf(rb1[2], rb1[3]));
  float ls = 0.f;
  for (int c = lo + tid; c < hi; c += 256) {
    float e = expf(probs[c] - bmax);
    probs[c] = e;
    ls += e;
  }
  ls = wave_sum(ls);
  if (!lane) rb2[wave] = ls;
  __syncthreads();
  float inv = 1.f / (rb2[0] + rb2[1] + rb2[2] + rb2[3]);
  for (int c = lo + tid; c < hi; c += 256) probs[c] *= inv;
  __syncthreads();

  // PV: thread handles 4 contiguous h; one uint2 load per col
  float a0 = 0.f, a1 = 0.f, a2 = 0.f, a3 = 0.f;
  const bf16_t* vp = vbase + 4 * tid;
  for (int c = lo; c < hi; ++c) {
    float p = probs[c];
    uint2 vv = *(const uint2*)(vp + (size_t)c * QKVLD);
    a0 += p * bf2f(vv.x & 0xffffu);
    a1 += p * bf2f(vv.x >> 16);
    a2 += p * bf2f(vv.y & 0xffffu);
    a3 += p * bf2f(vv.y >> 16);
  }
  uint2 pk;
  pk.x = (unsigned int)f2bf(a0) | ((unsigned int)f2bf(a1) << 16);
  pk.y = (unsigned int)f2bf(a2) | ((unsigned int)f2bf(a3) << 16);
  *(uint2*)(qp + 4 * tid) = pk;  // av over own Q row (reads done pre-barrier)
}

extern "C" void kernel_launch(void* const* d_in, const int* in_sizes, int n_in,
                              void* d_out, int out_size, void* d_ws, size_t ws_size,
                              hipStream_t stream) {
  (void)in_sizes; (void)n_in; (void)out_size; (void)ws_size;
  const float* z = (const float*)d_in[0];
  const float* cls = (const float*)d_in[1];
  const float* ln_g = (const float*)d_in[2];
  const float* ln_b = (const float*)d_in[3];
  const float* w_qkv = (const float*)d_in[4];
  const float* b_qkv = (const float*)d_in[5];
  const float* w_o = (const float*)d_in[6];
  const float* b_o = (const float*)d_in[7];
  const float* w_m1 = (const float*)d_in[8];
  const float* b_m1 = (const float*)d_in[9];
  const float* w_m2 = (const float*)d_in[10];
  const float* b_m2 = (const float*)d_in[11];

  // ws: [wt_m2 2MB][pe 0.6MB][qkv 118MB] = ~120.7 MB
  char* wsb = (char*)d_ws;
  bf16_t* wt_m2 = (bf16_t*)wsb;
  float* pe = (float*)(wsb + 2097152);
  bf16_t* qkv = (bf16_t*)(wsb + 2097152 + 614400);

  // d_out scratch: [x bf16 39.3MB][wt_qkv 6.3MB][wt_o 2MB][wt_m1 2MB]
  char* outb = (char*)d_out;
  bf16_t* x = (bf16_t*)outb;
  bf16_t* wt_qkv = (bf16_t*)(outb + 39321600);
  bf16_t* wt_o = (bf16_t*)(outb + 45613056);
  bf16_t* wt_m1 = (bf16_t*)(outb + 47710208);

  bf16_t* av = qkv;            // attention writes over Q slice
  bf16_t* sa = qkv + HD;       // over K slice
  bf16_t* zsa = qkv + 2 * HD;  // over V slice
  bf16_t* h1 = qkv;            // over Q slice (av dead)
  float* out = (float*)d_out;

  transpose_kernel<<<dim3(96, 32), dim3(32, 8), 0, stream>>>(w_qkv, wt_qkv, HD, 3 * HD);
  transpose_kernel<<<dim3(32, 32), dim3(32, 8), 0, stream>>>(w_o, wt_o, HD, HD);
  transpose_kernel<<<dim3(32, 32), dim3(32, 8), 0, stream>>>(w_m1, wt_m1, HD, HD);
  transpose_kernel<<<dim3(32, 32), dim3(32, 8), 0, stream>>>(w_m2, wt_m2, HD, HD);
  pe_kernel<<<S1, 256, 0, stream>>>(pe);
  build_x_kernel<<<MTOK, 256, 0, stream>>>(z, cls, pe, ln_g, ln_b, x);
  mfma_gemm_kernel<0><<<dim3(24, 150), 256, 0, stream>>>(
      x, HD, wt_qkv, b_qkv, qkv, QKVLD, 3 * HD);
  attn_kernel<<<dim3(S1, BATCH), 256, 0, stream>>>(qkv);
  mfma_gemm_kernel<0><<<dim3(8, 150), 256, 0, stream>>>(
      av, QKVLD, wt_o, b_o, sa, QKVLD, HD);
  ln_residual_kernel<<<MTOK, 256, 0, stream>>>(sa, x, ln_g, ln_b, zsa);
  mfma_gemm_kernel<1><<<dim3(8, 150), 256, 0, stream>>>(
      zsa, QKVLD, wt_m1, b_m1, h1, QKVLD, HD);
  mfma_gemm_out_kernel<<<dim3(8, 150), 256, 0, stream>>>(
      h1, QKVLD, wt_m2, b_m2, zsa, out);
}

// Round 5
// 741.825 us; speedup vs baseline: 5.2420x; 1.0815x over previous
//
#include <hip/hip_runtime.h>
#include <math.h>

#define HD 1024
#define S1 150
#define BATCH 128
#define MTOK (S1 * BATCH) /* 19200 */
#define WIN 20
#define QKVLD (3 * HD) /* 3072 */

typedef unsigned short bf16_t;
typedef short s16x8 __attribute__((ext_vector_type(8)));
typedef float f32x4 __attribute__((ext_vector_type(4)));

__device__ __forceinline__ float bf2f(unsigned int u16) {
  return __uint_as_float(u16 << 16);
}
__device__ __forceinline__ unsigned short f2bf(float f) {
  unsigned int u = __float_as_uint(f);
  u += 0x7fff + ((u >> 16) & 1);  // RNE
  return (unsigned short)(u >> 16);
}

__device__ __forceinline__ float wave_sum(float v) {
#pragma unroll
  for (int o = 32; o; o >>= 1) v += __shfl_down(v, o, 64);
  return v;
}
__device__ __forceinline__ float wave_max(float v) {
#pragma unroll
  for (int o = 32; o; o >>= 1) v = fmaxf(v, __shfl_down(v, o, 64));
  return v;
}

// async 16B/lane global->LDS. LDS dest = wave-uniform base + lane*16.
__device__ __forceinline__ void gload_lds16(const bf16_t* g, bf16_t* l) {
  __builtin_amdgcn_global_load_lds(
      (const __attribute__((address_space(1))) unsigned int*)(unsigned long long)(const void*)g,
      (__attribute__((address_space(3))) unsigned int*)(unsigned int)(unsigned long long)(void*)l,
      16, 0, 0);
}

// ---------------- weight transpose+convert: WT[n][k] = bf16(W[k][n]) ------
__global__ __launch_bounds__(256) void transpose_kernel(
    const float* __restrict__ W, bf16_t* __restrict__ WT, int K, int N) {
  __shared__ float t[32][33];
  int n0 = blockIdx.x * 32, k0 = blockIdx.y * 32;
  int tx = threadIdx.x, ty = threadIdx.y;
#pragma unroll
  for (int i = 0; i < 4; i++)
    t[ty + i * 8][tx] = W[(size_t)(k0 + ty + i * 8) * N + n0 + tx];
  __syncthreads();
#pragma unroll
  for (int i = 0; i < 4; i++)
    WT[(size_t)(n0 + ty + i * 8) * K + k0 + tx] = f2bf(t[tx][ty + i * 8]);
}

// ---------------- PE table ------------------------------------------------
__global__ void pe_kernel(float* __restrict__ pe) {
  int s = blockIdx.x;
  double pos = 6.283185307179586476925286766559 * (double)s;
  for (int p = threadIdx.x; p < HD / 2; p += blockDim.x) {
    double dv = exp((double)(2 * p) * (-9.210340371976184 / (double)HD));
    double a = pos * dv;
    pe[s * HD + 2 * p] = (float)sin(a);
    pe[s * HD + 2 * p + 1] = (float)cos(a);
  }
}

// ---------------- x = bf16(LN(concat(cls, z^T) + pe)) ---------------------
__global__ __launch_bounds__(256) void build_x_kernel(
    const float* __restrict__ z, const float* __restrict__ cls,
    const float* __restrict__ pe, const float* __restrict__ g,
    const float* __restrict__ be, bf16_t* __restrict__ x) {
  int t = blockIdx.x;
  int b = t / S1, s = t % S1;
  const float* src = (s == 0) ? cls : (z + ((size_t)(s - 1) * BATCH + b) * HD);
  const float* pr = pe + (size_t)s * HD;
  int tid = threadIdx.x;
  float vals[4];
  float sum = 0.f, sq = 0.f;
#pragma unroll
  for (int i = 0; i < 4; i++) {
    int h = tid + i * 256;
    float v = src[h] + pr[h];
    vals[i] = v;
    sum += v;
    sq += v * v;
  }
  __shared__ float shs[4], shq[4];
  __shared__ float sm, sr;
  sum = wave_sum(sum);
  sq = wave_sum(sq);
  int wave = tid >> 6, lane = tid & 63;
  if (!lane) { shs[wave] = sum; shq[wave] = sq; }
  __syncthreads();
  if (!tid) {
    float S = shs[0] + shs[1] + shs[2] + shs[3];
    float Q = shq[0] + shq[1] + shq[2] + shq[3];
    float mean = S * (1.f / HD);
    float var = Q * (1.f / HD) - mean * mean;
    sm = mean;
    sr = rsqrtf(var + 1e-5f);
  }
  __syncthreads();
  float mean = sm, rstd = sr;
  bf16_t* xr = x + (size_t)t * HD;
#pragma unroll
  for (int i = 0; i < 4; i++) {
    int h = tid + i * 256;
    xr[h] = f2bf((vals[i] - mean) * rstd * g[h] + be[h]);
  }
}

// ---------------- zsa = bf16(LN(sa + x)) ----------------------------------
__global__ __launch_bounds__(256) void ln_residual_kernel(
    const bf16_t* __restrict__ a, const bf16_t* __restrict__ r,
    const float* __restrict__ g, const float* __restrict__ be,
    bf16_t* __restrict__ out) {
  int t = blockIdx.x;
  int tid = threadIdx.x;
  const bf16_t* ar = a + (size_t)t * QKVLD;
  const bf16_t* rr = r + (size_t)t * HD;
  float vals[4];
  float sum = 0.f, sq = 0.f;
#pragma unroll
  for (int i = 0; i < 4; i++) {
    int h = tid + i * 256;
    float v = bf2f(ar[h]) + bf2f(rr[h]);
    vals[i] = v;
    sum += v;
    sq += v * v;
  }
  __shared__ float shs[4], shq[4];
  __shared__ float sm, sr;
  sum = wave_sum(sum);
  sq = wave_sum(sq);
  int wave = tid >> 6, lane = tid & 63;
  if (!lane) { shs[wave] = sum; shq[wave] = sq; }
  __syncthreads();
  if (!tid) {
    float S = shs[0] + shs[1] + shs[2] + shs[3];
    float Q = shq[0] + shq[1] + shq[2] + shq[3];
    float mean = S * (1.f / HD);
    float var = Q * (1.f / HD) - mean * mean;
    sm = mean;
    sr = rsqrtf(var + 1e-5f);
  }
  __syncthreads();
  float mean = sm, rstd = sr;
  bf16_t* outp = out + (size_t)t * QKVLD;
#pragma unroll
  for (int i = 0; i < 4; i++) {
    int h = tid + i * 256;
    outp[h] = f2bf((vals[i] - mean) * rstd * g[h] + be[h]);
  }
}

// ---------------- MFMA GEMM: C(bf16) = A(M x 1024, bf16) @ WT^T + bias ----
template <int EPI>
__global__ __launch_bounds__(256) void mfma_gemm_kernel(
    const bf16_t* __restrict__ A, int lda, const bf16_t* __restrict__ WT,
    const float* __restrict__ bias, bf16_t* __restrict__ C, int ldc, int N) {
  constexpr int K = 1024;
  __shared__ bf16_t As[128 * 32];
  __shared__ bf16_t Bs[128 * 32];
  int tid = threadIdx.x;
  int w = tid >> 6, lane = tid & 63;
  int wm = w >> 1, wn = w & 1;
  int m0 = blockIdx.y * 128, n0 = blockIdx.x * 128;

  int srow = lane >> 2;
  int scol = ((lane & 3) ^ ((lane >> 3) & 3)) * 8;
  const bf16_t* gA0 = A + (size_t)(m0 + w * 32 + srow) * lda + scol;
  const bf16_t* gA1 = gA0 + (size_t)16 * lda;
  const bf16_t* gB0 = WT + (size_t)(n0 + w * 32 + srow) * K + scol;
  const bf16_t* gB1 = gB0 + (size_t)16 * K;
  bf16_t* lA0 = As + (w * 32) * 32;
  bf16_t* lA1 = As + (w * 32 + 16) * 32;
  bf16_t* lB0 = Bs + (w * 32) * 32;
  bf16_t* lB1 = Bs + (w * 32 + 16) * 32;

  int frow = lane & 15;
  int slot = (lane >> 4) ^ ((frow >> 1) & 3);
  int aoff[4], boff[4];
#pragma unroll
  for (int t = 0; t < 4; t++) {
    aoff[t] = (wm * 64 + t * 16 + frow) * 32 + slot * 8;
    boff[t] = (wn * 64 + t * 16 + frow) * 32 + slot * 8;
  }

  f32x4 acc[4][4] = {};

  for (int k0 = 0; k0 < K; k0 += 32) {
    gload_lds16(gA0, lA0);
    gload_lds16(gA1, lA1);
    gload_lds16(gB0, lB0);
    gload_lds16(gB1, lB1);
    gA0 += 32; gA1 += 32; gB0 += 32; gB1 += 32;
    __syncthreads();
    s16x8 af[4], bf[4];
#pragma unroll
    for (int t = 0; t < 4; t++) {
      af[t] = *(const s16x8*)(As + aoff[t]);
      bf[t] = *(const s16x8*)(Bs + boff[t]);
    }
#pragma unroll
    for (int i = 0; i < 4; i++)
#pragma unroll
      for (int j = 0; j < 4; j++)
        acc[i][j] = __builtin_amdgcn_mfma_f32_16x16x32_bf16(af[i], bf[j], acc[i][j], 0, 0, 0);
    __syncthreads();
  }

  int erow = (lane >> 4) * 4, ecol = lane & 15;
#pragma unroll
  for (int j = 0; j < 4; j++) {
    int n = n0 + wn * 64 + j * 16 + ecol;
    float bb = bias[n];
#pragma unroll
    for (int i = 0; i < 4; i++) {
      int mb = m0 + wm * 64 + i * 16 + erow;
#pragma unroll
      for (int r = 0; r < 4; r++) {
        float v = acc[i][j][r] + bb;
        if (EPI == 1) v = 0.5f * v * (1.f + erff(v * 0.7071067811865476f));
        C[(size_t)(mb + r) * ldc + n] = f2bf(v);
      }
    }
  }
}

// ---------------- final MFMA GEMM: out[s,b,:] = res + A @ WT^T + bias -----
__global__ __launch_bounds__(256) void mfma_gemm_out_kernel(
    const bf16_t* __restrict__ A, int lda, const bf16_t* __restrict__ WT,
    const float* __restrict__ bias, const bf16_t* __restrict__ res,
    float* __restrict__ out) {
  constexpr int K = 1024;
  __shared__ bf16_t As[128 * 32];
  __shared__ bf16_t Bs[128 * 32];
  int tid = threadIdx.x;
  int w = tid >> 6, lane = tid & 63;
  int wm = w >> 1, wn = w & 1;
  int m0 = blockIdx.y * 128, n0 = blockIdx.x * 128;

  int srow = lane >> 2;
  int scol = ((lane & 3) ^ ((lane >> 3) & 3)) * 8;
  const bf16_t* gA0 = A + (size_t)(m0 + w * 32 + srow) * lda + scol;
  const bf16_t* gA1 = gA0 + (size_t)16 * lda;
  const bf16_t* gB0 = WT + (size_t)(n0 + w * 32 + srow) * K + scol;
  const bf16_t* gB1 = gB0 + (size_t)16 * K;
  bf16_t* lA0 = As + (w * 32) * 32;
  bf16_t* lA1 = As + (w * 32 + 16) * 32;
  bf16_t* lB0 = Bs + (w * 32) * 32;
  bf16_t* lB1 = Bs + (w * 32 + 16) * 32;

  int frow = lane & 15;
  int slot = (lane >> 4) ^ ((frow >> 1) & 3);
  int aoff[4], boff[4];
#pragma unroll
  for (int t = 0; t < 4; t++) {
    aoff[t] = (wm * 64 + t * 16 + frow) * 32 + slot * 8;
    boff[t] = (wn * 64 + t * 16 + frow) * 32 + slot * 8;
  }

  f32x4 acc[4][4] = {};

  for (int k0 = 0; k0 < K; k0 += 32) {
    gload_lds16(gA0, lA0);
    gload_lds16(gA1, lA1);
    gload_lds16(gB0, lB0);
    gload_lds16(gB1, lB1);
    gA0 += 32; gA1 += 32; gB0 += 32; gB1 += 32;
    __syncthreads();
    s16x8 af[4], bf[4];
#pragma unroll
    for (int t = 0; t < 4; t++) {
      af[t] = *(const s16x8*)(As + aoff[t]);
      bf[t] = *(const s16x8*)(Bs + boff[t]);
    }
#pragma unroll
    for (int i = 0; i < 4; i++)
#pragma unroll
      for (int j = 0; j < 4; j++)
        acc[i][j] = __builtin_amdgcn_mfma_f32_16x16x32_bf16(af[i], bf[j], acc[i][j], 0, 0, 0);
    __syncthreads();
  }

  int erow = (lane >> 4) * 4, ecol = lane & 15;
#pragma unroll
  for (int j = 0; j < 4; j++) {
    int n = n0 + wn * 64 + j * 16 + ecol;
    float bb = bias[n];
#pragma unroll
    for (int i = 0; i < 4; i++) {
      int mb = m0 + wm * 64 + i * 16 + erow;
#pragma unroll
      for (int r = 0; r < 4; r++) {
        int m = mb + r;
        int b = m / S1, s = m % S1;
        float v = acc[i][j][r] + bb + bf2f(res[(size_t)m * QKVLD + n]);
        out[((size_t)s * BATCH + b) * HD + n] = v;
      }
    }
  }
}

// ---------------- fused band attention, vectorized, XCD-swizzled ----------
// 1D grid of MTOK blocks. tok = (lin&7)*2400 + (lin>>3): under round-robin
// block->XCD dealing, XCD x owns a contiguous run of 2400 tokens (16 whole
// batches), so the sliding K/V band (~160 KB) stays resident in its 4 MB L2.
__global__ __launch_bounds__(256) void attn_kernel(bf16_t* __restrict__ qkv) {
  int lin = blockIdx.x;
  int tok = ((lin & 7) * (MTOK / 8)) + (lin >> 3);
  int b = tok / S1, qi = tok % S1;
  bf16_t* qp = qkv + (size_t)tok * QKVLD;
  const bf16_t* kbase = qkv + (size_t)b * S1 * QKVLD + HD;
  const bf16_t* vbase = qkv + (size_t)b * S1 * QKVLD + 2 * HD;
  __shared__ float probs[S1];
  __shared__ float rb1[4], rb2[4];
  int tid = threadIdx.x;
  int wave = tid >> 6, lane = tid & 63;
  int lo = (qi == 0) ? 0 : (qi - WIN > 0 ? qi - WIN : 0);
  int hi = (qi == 0) ? S1 : (qi + WIN < S1 ? qi + WIN : S1);

  // Q row -> registers: lane holds elems [lane*16, lane*16+16)
  float qf[16];
  {
    uint4 a = *(const uint4*)(qp + lane * 16);
    uint4 c4 = *(const uint4*)(qp + lane * 16 + 8);
    unsigned int u[8] = {a.x, a.y, a.z, a.w, c4.x, c4.y, c4.z, c4.w};
#pragma unroll
    for (int i = 0; i < 8; i++) {
      qf[2 * i] = bf2f(u[i] & 0xffffu);
      qf[2 * i + 1] = bf2f(u[i] >> 16);
    }
  }

  // scores: waves take cols round-robin; 2 vector loads per col
  for (int c = lo + wave; c < hi; c += 4) {
    const bf16_t* kr = kbase + (size_t)c * QKVLD + lane * 16;
    uint4 a = *(const uint4*)kr;
    uint4 c4 = *(const uint4*)(kr + 8);
    unsigned int u[8] = {a.x, a.y, a.z, a.w, c4.x, c4.y, c4.z, c4.w};
    float s = 0.f;
#pragma unroll
    for (int i = 0; i < 8; i++) {
      s += qf[2 * i] * bf2f(u[i] & 0xffffu);
      s += qf[2 * i + 1] * bf2f(u[i] >> 16);
    }
    s = wave_sum(s);
    if (!lane) probs[c] = s * 0.03125f;  // 1/sqrt(1024)
  }
  __syncthreads();

  // softmax over [lo,hi)
  float lm = -1e30f;
  for (int c = lo + tid; c < hi; c += 256) lm = fmaxf(lm, probs[c]);
  lm = wave_max(lm);
  if (!lane) rb1[wave] = lm;
  __syncthreads();
  float bmax = fmaxf(fmaxf(rb1[0], rb1[1]), fmaxf(rb1[2], rb1[3]));
  float ls = 0.f;
  for (int c = lo + tid; c < hi; c += 256) {
    float e = expf(probs[c] - bmax);
    probs[c] = e;
    ls += e;
  }
  ls = wave_sum(ls);
  if (!lane) rb2[wave] = ls;
  __syncthreads();
  float inv = 1.f / (rb2[0] + rb2[1] + rb2[2] + rb2[3]);
  for (int c = lo + tid; c < hi; c += 256) probs[c] *= inv;
  __syncthreads();

  // PV: thread handles 4 contiguous h; one uint2 load per col
  float a0 = 0.f, a1 = 0.f, a2 = 0.f, a3 = 0.f;
  const bf16_t* vp = vbase + 4 * tid;
  for (int c = lo; c < hi; ++c) {
    float p = probs[c];
    uint2 vv = *(const uint2*)(vp + (size_t)c * QKVLD);
    a0 += p * bf2f(vv.x & 0xffffu);
    a1 += p * bf2f(vv.x >> 16);
    a2 += p * bf2f(vv.y & 0xffffu);
    a3 += p * bf2f(vv.y >> 16);
  }
  uint2 pk;
  pk.x = (unsigned int)f2bf(a0) | ((unsigned int)f2bf(a1) << 16);
  pk.y = (unsigned int)f2bf(a2) | ((unsigned int)f2bf(a3) << 16);
  *(uint2*)(qp + 4 * tid) = pk;  // av over own Q row (reads done pre-barrier)
}

extern "C" void kernel_launch(void* const* d_in, const int* in_sizes, int n_in,
                              void* d_out, int out_size, void* d_ws, size_t ws_size,
                              hipStream_t stream) {
  (void)in_sizes; (void)n_in; (void)out_size; (void)ws_size;
  const float* z = (const float*)d_in[0];
  const float* cls = (const float*)d_in[1];
  const float* ln_g = (const float*)d_in[2];
  const float* ln_b = (const float*)d_in[3];
  const float* w_qkv = (const float*)d_in[4];
  const float* b_qkv = (const float*)d_in[5];
  const float* w_o = (const float*)d_in[6];
  const float* b_o = (const float*)d_in[7];
  const float* w_m1 = (const float*)d_in[8];
  const float* b_m1 = (const float*)d_in[9];
  const float* w_m2 = (const float*)d_in[10];
  const float* b_m2 = (const float*)d_in[11];

  // ws: [wt_m2 2MB][pe 0.6MB][qkv 118MB] = ~120.7 MB
  char* wsb = (char*)d_ws;
  bf16_t* wt_m2 = (bf16_t*)wsb;
  float* pe = (float*)(wsb + 2097152);
  bf16_t* qkv = (bf16_t*)(wsb + 2097152 + 614400);

  // d_out scratch: [x bf16 39.3MB][wt_qkv 6.3MB][wt_o 2MB][wt_m1 2MB]
  char* outb = (char*)d_out;
  bf16_t* x = (bf16_t*)outb;
  bf16_t* wt_qkv = (bf16_t*)(outb + 39321600);
  bf16_t* wt_o = (bf16_t*)(outb + 45613056);
  bf16_t* wt_m1 = (bf16_t*)(outb + 47710208);

  bf16_t* av = qkv;            // attention writes over Q slice
  bf16_t* sa = qkv + HD;       // over K slice
  bf16_t* zsa = qkv + 2 * HD;  // over V slice
  bf16_t* h1 = qkv;            // over Q slice (av dead)
  float* out = (float*)d_out;

  transpose_kernel<<<dim3(96, 32), dim3(32, 8), 0, stream>>>(w_qkv, wt_qkv, HD, 3 * HD);
  transpose_kernel<<<dim3(32, 32), dim3(32, 8), 0, stream>>>(w_o, wt_o, HD, HD);
  transpose_kernel<<<dim3(32, 32), dim3(32, 8), 0, stream>>>(w_m1, wt_m1, HD, HD);
  transpose_kernel<<<dim3(32, 32), dim3(32, 8), 0, stream>>>(w_m2, wt_m2, HD, HD);
  pe_kernel<<<S1, 256, 0, stream>>>(pe);
  build_x_kernel<<<MTOK, 256, 0, stream>>>(z, cls, pe, ln_g, ln_b, x);
  mfma_gemm_kernel<0><<<dim3(24, 150), 256, 0, stream>>>(
      x, HD, wt_qkv, b_qkv, qkv, QKVLD, 3 * HD);
  attn_kernel<<<MTOK, 256, 0, stream>>>(qkv);
  mfma_gemm_kernel<0><<<dim3(8, 150), 256, 0, stream>>>(
      av, QKVLD, wt_o, b_o, sa, QKVLD, HD);
  ln_residual_kernel<<<MTOK, 256, 0, stream>>>(sa, x, ln_g, ln_b, zsa);
  mfma_gemm_kernel<1><<<dim3(8, 150), 256, 0, stream>>>(
      zsa, QKVLD, wt_m1, b_m1, h1, QKVLD, HD);
  mfma_gemm_out_kernel<<<dim3(8, 150), 256, 0, stream>>>(
      h1, QKVLD, wt_m2, b_m2, zsa, out);
}